// Round 11
// baseline (364.442 us; speedup 1.0000x reference)
//
#include <hip/hip_runtime.h>

// out = X · M,  M = (W^T W)/32 (symmetric 1024x1024)
// X: 65536x1024 fp32.  W: 1024x1024 fp32.  out: 65536x1024 fp32.
// Path A (ws >= 131 MB, empirically true on this harness since R2):
//   K1 prep: X->bf16 convert (2048 blocks) with M-blocks INTERLEAVED every
//      9th block (co-residency: R2 M-last=143us, R3 M-first=103us were
//      dispatch-order serialized; interleave -> max(61,~40) ~= 70-85us).
//   K2 gemm_pg: 256x256, BK=32, 8 waves (2Mx4N, wave tile 128x64), ONE
//      barrier/K-tile, 4-slot ring per operand (128 KB), BOTH operands via
//      global_load_lds (pre-swizzled source, linear dest). Counted vmcnt:
//      issue batch(j+2)=4 loads at iter j; end-of-iter VMC(4) forces
//      batch(j+1) BEFORE the closing BAR (cross-wave-safe publish);
//      VMC(0) at j=30. No in-loop cvt (R4/R7/R10's invariant 26%-MfmaUtil
//      plateau across 3 sync structures isolates the fused-cvt A-path as
//      the suspect; R3 pure-gload measured 184us with a worse schedule).
// Path B (small ws): R1's proven fused kernel (Mb only, 2 MB).

typedef unsigned short u16;
typedef unsigned int u32;
typedef __bf16 bf16x8 __attribute__((ext_vector_type(8)));
typedef float f32x4 __attribute__((ext_vector_type(4)));

#define BAR() __builtin_amdgcn_s_barrier()
#define VMC(n) asm volatile("s_waitcnt vmcnt(" #n ")" ::: "memory")
#define SCHED0() __builtin_amdgcn_sched_barrier(0)

__device__ __forceinline__ u16 f2bf(float f) {  // RNE fp32->bf16
  u32 u = __float_as_uint(f);
  u += 0x7fffu + ((u >> 16) & 1u);
  return (u16)(u >> 16);
}

__device__ __forceinline__ void gload_lds16(const void* g, void* l) {
  __builtin_amdgcn_global_load_lds((const __attribute__((address_space(1))) u32*)g,
                                   (__attribute__((address_space(3))) u32*)l,
                                   16, 0, 0);
}

// ---------------- K1: interleaved {convert X -> bf16 ; M = (W^T W)/32} -------
// 2304 blocks: bid%9==8 -> M-tile block (256 of them); else convert block
// (2048 of them, cid = bid - bid/9).
__global__ __launch_bounds__(256) void prep(const float* __restrict__ X,
                                            const float* __restrict__ W,
                                            u16* __restrict__ Xb,
                                            u16* __restrict__ Mb) {
  __shared__ float w1[32][64];
  __shared__ float w2[32][64];
  const int bid = blockIdx.x;
  const int t = threadIdx.x;
  if ((bid % 9) != 8) {
    // ---- convert: 64M floats, float4 -> 4x bf16, coalesced streaming ----
    const int cid = bid - bid / 9;  // 0..2047
    const size_t stride = 2048 * 256;
    size_t idx = (size_t)cid * 256 + t;
#pragma unroll 4
    for (int it = 0; it < 32; ++it, idx += stride) {
      const float4 v = *(const float4*)(X + idx * 4);
      ushort4 d;
      d.x = f2bf(v.x); d.y = f2bf(v.y); d.z = f2bf(v.z); d.w = f2bf(v.w);
      *(ushort4*)(Xb + idx * 4) = d;
    }
    return;
  }
  // ---- M = (W^T W)/32, 64x64 tile per block ----
  const int mb = bid / 9;  // 0..255
  const int i0 = (mb >> 4) * 64;
  const int j0 = (mb & 15) * 64;
  const int tx = t & 15, ty = t >> 4;
  float acc[4][4] = {};
  for (int u0 = 0; u0 < 1024; u0 += 32) {
    __syncthreads();
#pragma unroll
    for (int p = 0; p < 2; ++p) {
      int idx = p * 256 + t;
      int lu = idx >> 4, lc = (idx & 15) * 4;
      *(float4*)&w1[lu][lc] = *(const float4*)(W + (size_t)(u0 + lu) * 1024 + i0 + lc);
      *(float4*)&w2[lu][lc] = *(const float4*)(W + (size_t)(u0 + lu) * 1024 + j0 + lc);
    }
    __syncthreads();
#pragma unroll 8
    for (int u = 0; u < 32; ++u) {
      float4 a = *(const float4*)&w1[u][ty * 4];
      float4 b = *(const float4*)&w2[u][tx * 4];
      float av[4] = {a.x, a.y, a.z, a.w};
      float bv[4] = {b.x, b.y, b.z, b.w};
#pragma unroll
      for (int e = 0; e < 4; ++e)
#pragma unroll
        for (int f = 0; f < 4; ++f)
          acc[e][f] += av[e] * bv[f];
    }
  }
  const float s = 0.03125f;
#pragma unroll
  for (int e = 0; e < 4; ++e) {
    ushort4 v;
    v.x = f2bf(acc[e][0] * s);
    v.y = f2bf(acc[e][1] * s);
    v.z = f2bf(acc[e][2] * s);
    v.w = f2bf(acc[e][3] * s);
    *(ushort4*)(Mb + (size_t)(i0 + ty * 4 + e) * 1024 + j0 + tx * 4) = v;
  }
}

// ---------------- K2: pure-gload_lds 1-barrier GEMM ---------------------------
// Ledger: iter j issues batch(j+2) = [A(2), B(2)] gload_lds (j<=29).
//  End of iter j: outstanding = [batch(j+1) 4, batch(j+2) 4] -> VMC(4) forces
//  batch(j+1); closing BAR publishes to all waves; iter j+1 reads slot (j+1)&3.
//  Tail: j=30 VMC(0) forces batch31. Prologue: batch0+batch1 then VMC(4)+BAR.
// Slot ring: read slot j&3, write slot (j+2)&3; one barrier/iter keeps waves
//  in the same region; a wave passes BAR only after its MFMAs issued, which
//  requires its ds_reads complete -> overwrite 2 barriers later is safe.
__global__ __launch_bounds__(512, 2) void gemm_pg(const u16* __restrict__ Xb,
                                                  const u16* __restrict__ Mb,
                                                  float* __restrict__ out) {
  __shared__ u16 lA[4][8192];  // 4 slots x 256 rows x 32 bf16 = 64 KB
  __shared__ u16 lB[4][8192];  // 64 KB

  const int p = blockIdx.x;                  // nwg = 1024 (%8==0)
  const int wg = (p & 7) * 128 + (p >> 3);   // chunked XCD swizzle
  const int bm = wg >> 2;                    // 0..255
  const int bn = wg & 3;                     // 0..3 (A-panel shared by 4 on XCD)
  const size_t r0 = (size_t)bm * 256;
  const int c0 = bn * 256;

  const int t = threadIdx.x;
  const int lane = t & 63;
  const int w = t >> 6;
  const int wr = w >> 2, wc = w & 3;         // 2x4 wave grid, wave tile 128x64
  const int fr = lane & 15;
  const int kc = lane >> 4;

  const int srow = t >> 2;                   // 0..127
  const int scl = t & 3;
  const int csw = scl ^ ((srow >> 1) & 3);   // XOR chunk swizzle (involution)
  const u16* gA  = Xb + (r0 + srow) * 1024 + csw * 8;          // pre-swz src
  const u16* gA2 = Xb + (r0 + 128 + srow) * 1024 + csw * 8;
  const u16* gB  = Mb + (size_t)(c0 + srow) * 1024 + csw * 8;
  const u16* gB2 = Mb + (size_t)(c0 + 128 + srow) * 1024 + csw * 8;
  u16* aDst = &lA[0][w * 512];               // wave-uniform linear dest
  u16* bDst = &lB[0][w * 512];

  f32x4 acc[8][4] = {};

  // ---- prologue: batch0 (slot0) + batch1 (slot1); VMC(4) forces batch0 ----
  gload_lds16(gA, aDst);            gload_lds16(gA2, aDst + 4096);
  gload_lds16(gB, bDst);            gload_lds16(gB2, bDst + 4096);
  gload_lds16(gA + 32, aDst + 8192); gload_lds16(gA2 + 32, aDst + 8192 + 4096);
  gload_lds16(gB + 32, bDst + 8192); gload_lds16(gB2 + 32, bDst + 8192 + 4096);
  VMC(4);
  SCHED0();
  BAR();

  for (int j = 0; j < 32; ++j) {
    const u16* bA = &lA[j & 3][0];
    const u16* bB = &lB[j & 3][0];
    const int sb = (j + 2) & 3;

    if (j <= 29) {  // stage batch(j+2) first (max time in flight)
      const int ko = (j + 2) * 32;
      gload_lds16(gA + ko, aDst + sb * 8192);
      gload_lds16(gA2 + ko, aDst + sb * 8192 + 4096);
      gload_lds16(gB + ko, bDst + sb * 8192);
      gload_lds16(gB2 + ko, bDst + sb * 8192 + 4096);
    }
    // fragment reads (compiler emits counted lgkmcnt before each MFMA)
    bf16x8 bf[4], af[8];
#pragma unroll
    for (int n = 0; n < 4; ++n) {
      const int row = wc * 64 + n * 16 + fr;
      const int cs = kc ^ ((row >> 1) & 3);
      bf[n] = *(const bf16x8*)&bB[row * 32 + cs * 8];
    }
#pragma unroll
    for (int m = 0; m < 8; ++m) {
      const int row = wr * 128 + m * 16 + fr;
      const int cs = kc ^ ((row >> 1) & 3);
      af[m] = *(const bf16x8*)&bA[row * 32 + cs * 8];
    }
    __builtin_amdgcn_s_setprio(1);
#pragma unroll
    for (int m = 0; m < 8; ++m)
#pragma unroll
      for (int n = 0; n < 4; ++n)
        acc[m][n] = __builtin_amdgcn_mfma_f32_16x16x32_bf16(af[m], bf[n],
                                                            acc[m][n], 0, 0, 0);
    __builtin_amdgcn_s_setprio(0);
    // cross-wave publish of batch(j+1) BEFORE the closing barrier
    if (j <= 29) {
      VMC(4);
    } else if (j == 30) {
      VMC(0);
    }
    SCHED0();
    BAR();
  }

  // ---- epilogue: C layout col=lane&15, row=(lane>>4)*4+reg ----
  const int ocol = lane & 15;
  const int orow = (lane >> 4) * 4;
#pragma unroll
  for (int m = 0; m < 8; ++m) {
    const size_t rbase = (r0 + wr * 128 + m * 16 + orow) * 1024;
#pragma unroll
    for (int n = 0; n < 4; ++n) {
      float* o = out + rbase + (c0 + wc * 64 + n * 16 + ocol);
      o[0] = acc[m][n][0];
      o[1024] = acc[m][n][1];
      o[2048] = acc[m][n][2];
      o[3072] = acc[m][n][3];
    }
  }
}

// ---------------- fallback (R1's proven fused kernel, needs only 2 MB ws) -----
__global__ __launch_bounds__(256) void gemm_fused(const float* __restrict__ X,
                                                  const u16* __restrict__ Mb,
                                                  float* __restrict__ out) {
  __shared__ u16 lA[128 * 32];
  __shared__ u16 lB[128 * 32];
  const int p = blockIdx.x;
  const int wg = (p & 7) * 512 + (p >> 3);
  const int bm = wg >> 3;
  const int bn = wg & 7;
  const size_t r0 = (size_t)bm * 128;
  const int c0 = bn * 128;
  const int t = threadIdx.x;
  const int lane = t & 63;
  const int w = t >> 6;
  const int wr = w >> 1, wc = w & 1;
  const int ar_base = t >> 3;
  const int ac = t & 7;
  const int a_chunk = ac >> 1;
  const int a_half = ac & 1;
  const int fr = lane & 15;
  const int kc = lane >> 4;
  f32x4 acc[4][4] = {};
  for (int k0 = 0; k0 < 1024; k0 += 32) {
#pragma unroll
    for (int i = 0; i < 2; ++i) {
      const int slot0 = w * 128 + i * 64;
      const int slot = slot0 + lane;
      const int nr = slot >> 2;
      const int cc = (slot & 3) ^ ((nr >> 1) & 3);
      const char* g = (const char*)(Mb + (size_t)(c0 + nr) * 1024 + k0) + cc * 16;
      gload_lds16(g, (void*)(lB + slot0 * 8));
    }
#pragma unroll
    for (int q = 0; q < 4; ++q) {
      const int ar = q * 32 + ar_base;
      const float4 v = *(const float4*)(X + (r0 + ar) * 1024 + k0 + ac * 4);
      uint2 d;
      d.x = (u32)f2bf(v.x) | ((u32)f2bf(v.y) << 16);
      d.y = (u32)f2bf(v.z) | ((u32)f2bf(v.w) << 16);
      const int cs = a_chunk ^ ((ar >> 1) & 3);
      *(uint2*)&lA[ar * 32 + cs * 8 + a_half * 4] = d;
    }
    __syncthreads();
    bf16x8 afr[4], bfr[4];
#pragma unroll
    for (int m = 0; m < 4; ++m) {
      const int row = wr * 64 + m * 16 + fr;
      const int cs = kc ^ ((row >> 1) & 3);
      afr[m] = *(const bf16x8*)&lA[row * 32 + cs * 8];
    }
#pragma unroll
    for (int n = 0; n < 4; ++n) {
      const int row = wc * 64 + n * 16 + fr;
      const int cs = kc ^ ((row >> 1) & 3);
      bfr[n] = *(const bf16x8*)&lB[row * 32 + cs * 8];
    }
#pragma unroll
    for (int m = 0; m < 4; ++m)
#pragma unroll
      for (int n = 0; n < 4; ++n)
        acc[m][n] = __builtin_amdgcn_mfma_f32_16x16x32_bf16(afr[m], bfr[n],
                                                            acc[m][n], 0, 0, 0);
    __syncthreads();
  }
  const int ocol = lane & 15;
  const int orow = (lane >> 4) * 4;
#pragma unroll
  for (int m = 0; m < 4; ++m) {
    const size_t rbase = (r0 + wr * 64 + m * 16 + orow) * 1024;
#pragma unroll
    for (int n = 0; n < 4; ++n) {
      float* o = out + rbase + (c0 + wc * 64 + n * 16 + ocol);
      o[0] = acc[m][n][0];
      o[1024] = acc[m][n][1];
      o[2048] = acc[m][n][2];
      o[3072] = acc[m][n][3];
    }
  }
}

__global__ __launch_bounds__(256) void compute_M_fb(const float* __restrict__ W,
                                                    u16* __restrict__ Mb) {
  __shared__ float w1[32][64];
  __shared__ float w2[32][64];
  const int t = threadIdx.x;
  const int i0 = blockIdx.y * 64;
  const int j0 = blockIdx.x * 64;
  const int tx = t & 15, ty = t >> 4;
  float acc[4][4] = {};
  for (int u0 = 0; u0 < 1024; u0 += 32) {
    __syncthreads();
#pragma unroll
    for (int p = 0; p < 2; ++p) {
      int idx = p * 256 + t;
      int lu = idx >> 4, lc = (idx & 15) * 4;
      *(float4*)&w1[lu][lc] = *(const float4*)(W + (size_t)(u0 + lu) * 1024 + i0 + lc);
      *(float4*)&w2[lu][lc] = *(const float4*)(W + (size_t)(u0 + lu) * 1024 + j0 + lc);
    }
    __syncthreads();
#pragma unroll 8
    for (int u = 0; u < 32; ++u) {
      float4 a = *(const float4*)&w1[u][ty * 4];
      float4 b = *(const float4*)&w2[u][tx * 4];
      float av[4] = {a.x, a.y, a.z, a.w};
      float bv[4] = {b.x, b.y, b.z, b.w};
#pragma unroll
      for (int e = 0; e < 4; ++e)
#pragma unroll
        for (int f = 0; f < 4; ++f)
          acc[e][f] += av[e] * bv[f];
    }
  }
  const float s = 0.03125f;
#pragma unroll
  for (int e = 0; e < 4; ++e) {
    ushort4 v;
    v.x = f2bf(acc[e][0] * s);
    v.y = f2bf(acc[e][1] * s);
    v.z = f2bf(acc[e][2] * s);
    v.w = f2bf(acc[e][3] * s);
    *(ushort4*)(Mb + (size_t)(i0 + ty * 4 + e) * 1024 + j0 + tx * 4) = v;
  }
}

extern "C" void kernel_launch(void* const* d_in, const int* in_sizes, int n_in,
                              void* d_out, int out_size, void* d_ws, size_t ws_size,
                              hipStream_t stream) {
  const float* X = (const float*)d_in[0];
  const float* W = (const float*)d_in[1];
  float* out = (float*)d_out;
  u16* Mb = (u16*)d_ws;                                 // 2 MB
  u16* Xb = (u16*)((char*)d_ws + (size_t)(1 << 21));    // 128 MB

  const size_t need = (size_t)(1 << 21) + (size_t)64 * 1024 * 1024 * 2;
  if (ws_size >= need) {
    prep<<<2304, 256, 0, stream>>>(X, W, Xb, Mb);
    gemm_pg<<<1024, 512, 0, stream>>>(Xb, Mb, out);
  } else {
    compute_M_fb<<<dim3(16, 16), 256, 0, stream>>>(W, Mb);
    gemm_fused<<<4096, 256, 0, stream>>>(X, Mb, out);
  }
}